// Round 5
// baseline (196.626 us; speedup 1.0000x reference)
//
#include <hip/hip_runtime.h>
#include <hip/hip_cooperative_groups.h>
#include <math.h>

namespace cg = cooperative_groups;

#define BB 8
#define LL 8192
#define CC 512
#define NCH 64    // stat chunks per b (128 rows each)

#define H0_OFF (BB*CC)            // 4096
#define A_OFF  (H0_OFF + BB*CC*4) // 20480

#define F_ALPHA_BASE 1.2f
#define F_ALPHA_SCALE 0.3f
#define F_GRAPH_LAMBDA 0.3f
#define F_FUSION_BETA 0.1f
#define F_PRIOR_BETA 0.2f
#define F_LN_EPS 1e-5f

struct P {
    const float* res; const float* ne;
    const float* Wl1; const float* bl1; const float* Wl2; const float* bl2;
    const float* Wg;  const float* bg;  const float* Wq;  const float* bq;
    const float* Wk;  const float* bk;  const float* Wf;  const float* bf;
    const float* Wo;  const float* bo;  const float* lng; const float* lnb;
    float* out; float* pbuf; float* prior;
};

// ---------- Phase 1: stats partials (512 blocks, 128-row slabs) ----------
__device__ __forceinline__ void phase_stats(const P& p, float* smem, int blk, int tid) {
    int b = blk >> 6, cb = blk & 63;
    int sub = tid >> 7;                  // 0/1: rows [0,64) vs [64,128) of slab
    int c4 = (tid & 127) * 4;
    const float* base = p.res + ((size_t)b * LL + cb * 128 + sub * 64) * CC + c4;
    float s0 = 0.f, s1 = 0.f, s2 = 0.f, s3 = 0.f;
    float m0 = 0.f, m1 = 0.f, m2 = 0.f, m3 = 0.f;
    float q0 = 0.f, q1 = 0.f, q2 = 0.f, q3 = 0.f;
    #pragma unroll 8
    for (int r = 0; r < 64; r++) {
        float4 v = *(const float4*)(base + (size_t)r * CC);
        s0 += fabsf(v.x); s1 += fabsf(v.y); s2 += fabsf(v.z); s3 += fabsf(v.w);
        m0 = fmaxf(m0, fabsf(v.x)); m1 = fmaxf(m1, fabsf(v.y));
        m2 = fmaxf(m2, fabsf(v.z)); m3 = fmaxf(m3, fabsf(v.w));
        q0 = fmaf(v.x, v.x, q0); q1 = fmaf(v.y, v.y, q1);
        q2 = fmaf(v.z, v.z, q2); q3 = fmaf(v.w, v.w, q3);
    }
    if (sub == 1) {
        *(float4*)&smem[0 * CC + c4] = make_float4(s0, s1, s2, s3);
        *(float4*)&smem[1 * CC + c4] = make_float4(m0, m1, m2, m3);
        *(float4*)&smem[2 * CC + c4] = make_float4(q0, q1, q2, q3);
    }
    __syncthreads();
    if (sub == 0) {
        float4 cs = *(const float4*)&smem[0 * CC + c4];
        float4 cm = *(const float4*)&smem[1 * CC + c4];
        float4 cq = *(const float4*)&smem[2 * CC + c4];
        s0 += cs.x; s1 += cs.y; s2 += cs.z; s3 += cs.w;
        m0 = fmaxf(m0, cm.x); m1 = fmaxf(m1, cm.y);
        m2 = fmaxf(m2, cm.z); m3 = fmaxf(m3, cm.w);
        q0 += cq.x; q1 += cq.y; q2 += cq.z; q3 += cq.w;
        float* pb = p.pbuf + ((size_t)(b * 3) * NCH + cb) * CC + c4;
        *(float4*)(pb)                      = make_float4(s0, s1, s2, s3);
        *(float4*)(pb + (size_t)NCH * CC)     = make_float4(m0, m1, m2, m3);
        *(float4*)(pb + (size_t)2 * NCH * CC) = make_float4(q0, q1, q2, q3);
    }
}

// ---------- Phase 2: h0 reduce (blocks<256) | prior (blocks in [256,512)) ----------
__device__ __forceinline__ void phase_mid(const P& p, float* smem, int blk, int tid) {
    if (blk < 256) {
        int b = blk >> 5, c16 = blk & 31;
        int coff = tid & 15;
        int part = tid >> 4;   // 0..15, 4 chunks each
        int c = c16 * 16 + coff;
        const float* pA = p.pbuf + ((size_t)(b * 3 + 0) * NCH + part * 4) * CC + c;
        const float* pB = p.pbuf + ((size_t)(b * 3 + 1) * NCH + part * 4) * CC + c;
        const float* pC = p.pbuf + ((size_t)(b * 3 + 2) * NCH + part * 4) * CC + c;
        float sum = 0.f, mx = 0.f, sq = 0.f;
        #pragma unroll
        for (int i = 0; i < 4; i++) {
            sum += pA[(size_t)i * CC];
            mx = fmaxf(mx, pB[(size_t)i * CC]);
            sq += pC[(size_t)i * CC];
        }
        sum += __shfl_xor(sum, 16); sum += __shfl_xor(sum, 32);
        mx = fmaxf(mx, __shfl_xor(mx, 16)); mx = fmaxf(mx, __shfl_xor(mx, 32));
        sq += __shfl_xor(sq, 16); sq += __shfl_xor(sq, 32);
        int w = tid >> 6;
        if ((tid & 63) < 16) {
            smem[(w * 3 + 0) * 16 + coff] = sum;
            smem[(w * 3 + 1) * 16 + coff] = mx;
            smem[(w * 3 + 2) * 16 + coff] = sq;
        }
        __syncthreads();
        if (tid < 16) {
            float ts = smem[0 * 16 + coff] + smem[3 * 16 + coff] + smem[6 * 16 + coff] + smem[9 * 16 + coff];
            float tm = fmaxf(fmaxf(smem[1 * 16 + coff], smem[4 * 16 + coff]),
                             fmaxf(smem[7 * 16 + coff], smem[10 * 16 + coff]));
            float tq = smem[2 * 16 + coff] + smem[5 * 16 + coff] + smem[8 * 16 + coff] + smem[11 * 16 + coff];
            float m = ts * (1.f / LL);
            float sqm = tq * (1.f / LL);
            float sd = sqrtf(fmaxf(sqm - m * m, 0.f));
            int g = b * CC + c16 * 16 + coff;
            *(float4*)(p.out + H0_OFF + (size_t)g * 4) = make_float4(m, tm, sd, sqm);
        }
    } else {
        int base_id = (blk - 256) * 1024 + tid;
        #pragma unroll
        for (int rep = 0; rep < 4; rep++) {
            int id = base_id + rep * 256;        // covers 0..262143 exactly
            int c = id >> 9, d = id & 511;
            const float4* a4 = (const float4*)(p.ne + (size_t)c * 16);
            const float4* b4 = (const float4*)(p.ne + (size_t)d * 16);
            float s = 0.f;
            #pragma unroll
            for (int t = 0; t < 4; t++) {
                float4 av = a4[t], bv = b4[t];
                s = fmaf(av.x, bv.x, s); s = fmaf(av.y, bv.y, s);
                s = fmaf(av.z, bv.z, s); s = fmaf(av.w, bv.w, s);
            }
            p.prior[id] = fmaxf(s, 0.f);
        }
    }
}

// ---------- Phase 3: rows (512 blocks, 8 rows each, 2 rows/wave) ----------
__device__ __forceinline__ void phase_rows(const P& p, float* smem, int blk, int tid) {
    int b = blk >> 6, rb = blk & 63;
    #pragma unroll
    for (int ccy = 0; ccy < 2; ccy++) {
        int col = tid + ccy * 256;
        float4 hv = *(const float4*)(p.out + H0_OFF + ((size_t)b * CC + col) * 4);
        smem[col] = hv.x;
        smem[CC + col] = hv.y;
        smem[2 * CC + col] = hv.z;
        smem[3 * CC + col] = hv.w;
    }
    __syncthreads();

    int wid = tid >> 6, lane = tid & 63;
    int row0 = rb * 8 + wid * 2;

    // linearized QK: per row, u = Wk^T (Wq s + bq), c0 = q·bk
    float sloc[2][4], u[2][4], c0[2];
    #pragma unroll
    for (int rr = 0; rr < 2; rr++) {
        int row = row0 + rr;
        float sv0 = smem[row], sv1 = smem[CC + row];
        float sv2 = smem[2 * CC + row], sv3 = smem[3 * CC + row];
        sloc[rr][0] = sv0; sloc[rr][1] = sv1; sloc[rr][2] = sv2; sloc[rr][3] = sv3;
        float uu0 = 0.f, uu1 = 0.f, uu2 = 0.f, uu3 = 0.f, cc = 0.f;
        #pragma unroll
        for (int i = 0; i < 16; i++) {
            float qi = p.bq[i];
            qi = fmaf(p.Wq[i * 4 + 0], sv0, qi);
            qi = fmaf(p.Wq[i * 4 + 1], sv1, qi);
            qi = fmaf(p.Wq[i * 4 + 2], sv2, qi);
            qi = fmaf(p.Wq[i * 4 + 3], sv3, qi);
            uu0 = fmaf(qi, p.Wk[i * 4 + 0], uu0);
            uu1 = fmaf(qi, p.Wk[i * 4 + 1], uu1);
            uu2 = fmaf(qi, p.Wk[i * 4 + 2], uu2);
            uu3 = fmaf(qi, p.Wk[i * 4 + 3], uu3);
            cc = fmaf(qi, p.bk[i], cc);
        }
        u[rr][0] = uu0; u[rr][1] = uu1; u[rr][2] = uu2; u[rr][3] = uu3;
        c0[rr] = cc;
    }

    const float* prow = p.prior + (size_t)row0 * CC;
    float sv[2][8];
    float mx0 = -1e30f, mx1 = -1e30f;
    #pragma unroll
    for (int j = 0; j < 8; j++) {
        int col = lane + 64 * j;
        float h0c = smem[col], h1c = smem[CC + col];
        float h2c = smem[2 * CC + col], h3c = smem[3 * CC + col];
        float d0 = c0[0], d1 = c0[1];
        d0 = fmaf(u[0][0], h0c, d0); d1 = fmaf(u[1][0], h0c, d1);
        d0 = fmaf(u[0][1], h1c, d0); d1 = fmaf(u[1][1], h1c, d1);
        d0 = fmaf(u[0][2], h2c, d0); d1 = fmaf(u[1][2], h2c, d1);
        d0 = fmaf(u[0][3], h3c, d0); d1 = fmaf(u[1][3], h3c, d1);
        float v0 = fmaxf(d0, 0.f) + F_PRIOR_BETA * prow[col] + (col == row0 ? 1.f : 0.f);
        float v1 = fmaxf(d1, 0.f) + F_PRIOR_BETA * prow[CC + col] + (col == row0 + 1 ? 1.f : 0.f);
        sv[0][j] = v0; sv[1][j] = v1;
        mx0 = fmaxf(mx0, v0); mx1 = fmaxf(mx1, v1);
    }
    #pragma unroll
    for (int o = 32; o; o >>= 1) {
        mx0 = fmaxf(mx0, __shfl_xor(mx0, o));
        mx1 = fmaxf(mx1, __shfl_xor(mx1, o));
    }

    float ls0 = 0.f, ls1 = 0.f;
    float T0[4] = {0.f, 0.f, 0.f, 0.f}, T1[4] = {0.f, 0.f, 0.f, 0.f};
    #pragma unroll
    for (int j = 0; j < 8; j++) {
        int col = lane + 64 * j;
        float e0 = expf(sv[0][j] - mx0);
        float e1 = expf(sv[1][j] - mx1);
        sv[0][j] = e0; sv[1][j] = e1;
        ls0 += e0; ls1 += e1;
        float h0c = smem[col], h1c = smem[CC + col];
        float h2c = smem[2 * CC + col], h3c = smem[3 * CC + col];
        T0[0] = fmaf(e0, h0c, T0[0]); T1[0] = fmaf(e1, h0c, T1[0]);
        T0[1] = fmaf(e0, h1c, T0[1]); T1[1] = fmaf(e1, h1c, T1[1]);
        T0[2] = fmaf(e0, h2c, T0[2]); T1[2] = fmaf(e1, h2c, T1[2]);
        T0[3] = fmaf(e0, h3c, T0[3]); T1[3] = fmaf(e1, h3c, T1[3]);
    }
    #pragma unroll
    for (int o = 32; o; o >>= 1) {
        ls0 += __shfl_xor(ls0, o); ls1 += __shfl_xor(ls1, o);
        T0[0] += __shfl_xor(T0[0], o); T1[0] += __shfl_xor(T1[0], o);
        T0[1] += __shfl_xor(T0[1], o); T1[1] += __shfl_xor(T1[1], o);
        T0[2] += __shfl_xor(T0[2], o); T1[2] += __shfl_xor(T1[2], o);
        T0[3] += __shfl_xor(T0[3], o); T1[3] += __shfl_xor(T1[3], o);
    }
    float inv0 = 1.f / ls0, inv1 = 1.f / ls1;

    float* arow = p.out + A_OFF + ((size_t)b * CC + row0) * CC;
    #pragma unroll
    for (int j = 0; j < 8; j++) {
        arow[lane + 64 * j]      = sv[0][j] * inv0;
        arow[CC + lane + 64 * j] = sv[1][j] * inv1;
    }

    #pragma unroll
    for (int rr = 0; rr < 2; rr++) {
        int row = row0 + rr;
        float inv = rr ? inv1 : inv0;
        float Ta = (rr ? T1[0] : T0[0]) * inv;
        float Tb = (rr ? T1[1] : T0[1]) * inv;
        float Tc = (rr ? T1[2] : T0[2]) * inv;
        float Td = (rr ? T1[3] : T0[3]) * inv;
        float* s2 = sloc[rr];

        float gcomb[16];
        #pragma unroll
        for (int h = 0; h < 16; h++) {
            float w0 = p.Wg[h * 4 + 0], w1 = p.Wg[h * 4 + 1];
            float w2 = p.Wg[h * 4 + 2], w3 = p.Wg[h * 4 + 3];
            float bgh = p.bg[h];
            float hg = bgh;
            hg = fmaf(w0, s2[0], hg); hg = fmaf(w1, s2[1], hg);
            hg = fmaf(w2, s2[2], hg); hg = fmaf(w3, s2[3], hg);
            float mg = bgh;
            mg = fmaf(w0, Ta, mg); mg = fmaf(w1, Tb, mg);
            mg = fmaf(w2, Tc, mg); mg = fmaf(w3, Td, mg);
            gcomb[h] = hg + F_GRAPH_LAMBDA * fmaxf(mg, 0.f);
        }

        float t1v[16];
        #pragma unroll
        for (int i = 0; i < 16; i++) {
            float a = p.bl1[i];
            #pragma unroll
            for (int j = 0; j < 4; j++) a = fmaf(p.Wl1[i * 4 + j], s2[j], a);
            t1v[i] = fmaxf(a, 0.f);
        }
        float hvec[16];
        float mu = 0.f;
        #pragma unroll
        for (int h = 0; h < 16; h++) {
            float hl = p.bl2[h];
            #pragma unroll
            for (int j = 0; j < 16; j++) hl = fmaf(p.Wl2[h * 16 + j], t1v[j], hl);
            float hv = hl + F_FUSION_BETA * gcomb[h];
            hvec[h] = hv;
            mu += hv;
        }
        mu *= (1.f / 16.f);
        float var = 0.f;
        #pragma unroll
        for (int h = 0; h < 16; h++) { float d = hvec[h] - mu; var = fmaf(d, d, var); }
        var *= (1.f / 16.f);
        float istd = 1.f / sqrtf(var + F_LN_EPS);
        float hn[16];
        #pragma unroll
        for (int h = 0; h < 16; h++) hn[h] = (hvec[h] - mu) * istd * p.lng[h] + p.lnb[h];

        float acc2 = p.bo[0];
        #pragma unroll
        for (int o = 0; o < 16; o++) {
            float f = p.bf[o];
            #pragma unroll
            for (int t = 0; t < 16; t++) f = fmaf(p.Wf[o * 16 + t], hn[t], f);
            acc2 = fmaf(p.Wo[o], fmaxf(f, 0.f), acc2);
        }
        float alpha = F_ALPHA_BASE + F_ALPHA_SCALE * tanhf(acc2);
        if (lane == 0) p.out[(size_t)b * CC + row] = alpha;
    }
}

// ---------- cooperative single-kernel path ----------
__global__ __launch_bounds__(256, 4) void k_all(P p) {
    __shared__ float smem[4 * CC];
    cg::grid_group grid = cg::this_grid();
    phase_stats(p, smem, blockIdx.x, threadIdx.x);
    grid.sync();
    phase_mid(p, smem, blockIdx.x, threadIdx.x);
    grid.sync();
    phase_rows(p, smem, blockIdx.x, threadIdx.x);
}

// ---------- fallback 3-kernel path (identical logic) ----------
__global__ __launch_bounds__(256, 4) void k_p1(P p) {
    __shared__ float smem[4 * CC];
    phase_stats(p, smem, blockIdx.x, threadIdx.x);
}
__global__ __launch_bounds__(256, 4) void k_p2(P p) {
    __shared__ float smem[4 * CC];
    phase_mid(p, smem, blockIdx.x, threadIdx.x);
}
__global__ __launch_bounds__(256, 4) void k_p3(P p) {
    __shared__ float smem[4 * CC];
    phase_rows(p, smem, blockIdx.x, threadIdx.x);
}

extern "C" void kernel_launch(void* const* d_in, const int* in_sizes, int n_in,
                              void* d_out, int out_size, void* d_ws, size_t ws_size,
                              hipStream_t stream) {
    P p;
    p.res = (const float*)d_in[0];
    p.ne  = (const float*)d_in[1];
    p.Wl1 = (const float*)d_in[2];
    p.bl1 = (const float*)d_in[3];
    p.Wl2 = (const float*)d_in[4];
    p.bl2 = (const float*)d_in[5];
    p.Wg  = (const float*)d_in[6];
    p.bg  = (const float*)d_in[7];
    p.Wq  = (const float*)d_in[8];
    p.bq  = (const float*)d_in[9];
    p.Wk  = (const float*)d_in[10];
    p.bk  = (const float*)d_in[11];
    p.Wf  = (const float*)d_in[12];
    p.bf  = (const float*)d_in[13];
    p.Wo  = (const float*)d_in[14];
    p.bo  = (const float*)d_in[15];
    p.lng = (const float*)d_in[16];
    p.lnb = (const float*)d_in[17];
    p.out  = (float*)d_out;
    p.pbuf = (float*)d_ws;                                  // [B][3][NCH][C] = 3.1 MB
    p.prior = (float*)d_ws + (size_t)BB * 3 * NCH * CC;     // [C][C] = 1 MB

    void* args[] = { &p };
    hipError_t err = hipLaunchCooperativeKernel((void*)k_all, dim3(512), dim3(256),
                                                args, 0, stream);
    if (err != hipSuccess) {
        k_p1<<<512, 256, 0, stream>>>(p);
        k_p2<<<512, 256, 0, stream>>>(p);
        k_p3<<<512, 256, 0, stream>>>(p);
    }
}

// Round 6
// 55.730 us; speedup vs baseline: 3.5282x; 3.5282x over previous
//
#include <hip/hip_runtime.h>
#include <math.h>

#define BB 8
#define LL 8192
#define CC 512
#define NCH 64    // stat chunks per b (128 rows each)

#define H0_OFF (BB*CC)            // 4096
#define A_OFF  (H0_OFF + BB*CC*4) // 20480

#define F_ALPHA_BASE 1.2f
#define F_ALPHA_SCALE 0.3f
#define F_GRAPH_LAMBDA 0.3f
#define F_FUSION_BETA 0.1f
#define F_PRIOR_BETA 0.2f
#define F_LN_EPS 1e-5f

struct P {
    const float* res; const float* ne;
    const float* Wl1; const float* bl1; const float* Wl2; const float* bl2;
    const float* Wg;  const float* bg;  const float* Wq;  const float* bq;
    const float* Wk;  const float* bk;  const float* Wf;  const float* bf;
    const float* Wo;  const float* bo;  const float* lng; const float* lnb;
    float* out; float* pbuf;
};

// ---------------- Kernel 1: stats partials ----------------
// 512 blocks x 256. Block = (b, 128-row slab); two 64-row halves combined via LDS.
// pbuf layout: [b][stat][chunk][c].
__global__ __launch_bounds__(256) void k_stats(P p) {
    __shared__ float smem[3 * CC];
    int b = blockIdx.x >> 6, cb = blockIdx.x & 63;
    int sub = threadIdx.x >> 7;
    int c4 = (threadIdx.x & 127) * 4;
    const float* base = p.res + ((size_t)b * LL + cb * 128 + sub * 64) * CC + c4;
    float s0 = 0.f, s1 = 0.f, s2 = 0.f, s3 = 0.f;
    float m0 = 0.f, m1 = 0.f, m2 = 0.f, m3 = 0.f;
    float q0 = 0.f, q1 = 0.f, q2 = 0.f, q3 = 0.f;
    #pragma unroll 8
    for (int r = 0; r < 64; r++) {
        float4 v = *(const float4*)(base + (size_t)r * CC);
        s0 += fabsf(v.x); s1 += fabsf(v.y); s2 += fabsf(v.z); s3 += fabsf(v.w);
        m0 = fmaxf(m0, fabsf(v.x)); m1 = fmaxf(m1, fabsf(v.y));
        m2 = fmaxf(m2, fabsf(v.z)); m3 = fmaxf(m3, fabsf(v.w));
        q0 = fmaf(v.x, v.x, q0); q1 = fmaf(v.y, v.y, q1);
        q2 = fmaf(v.z, v.z, q2); q3 = fmaf(v.w, v.w, q3);
    }
    if (sub == 1) {
        *(float4*)&smem[0 * CC + c4] = make_float4(s0, s1, s2, s3);
        *(float4*)&smem[1 * CC + c4] = make_float4(m0, m1, m2, m3);
        *(float4*)&smem[2 * CC + c4] = make_float4(q0, q1, q2, q3);
    }
    __syncthreads();
    if (sub == 0) {
        float4 cs = *(const float4*)&smem[0 * CC + c4];
        float4 cm = *(const float4*)&smem[1 * CC + c4];
        float4 cq = *(const float4*)&smem[2 * CC + c4];
        s0 += cs.x; s1 += cs.y; s2 += cs.z; s3 += cs.w;
        m0 = fmaxf(m0, cm.x); m1 = fmaxf(m1, cm.y);
        m2 = fmaxf(m2, cm.z); m3 = fmaxf(m3, cm.w);
        q0 += cq.x; q1 += cq.y; q2 += cq.z; q3 += cq.w;
        float* pb = p.pbuf + ((size_t)(b * 3) * NCH + cb) * CC + c4;
        *(float4*)(pb)                        = make_float4(s0, s1, s2, s3);
        *(float4*)(pb + (size_t)NCH * CC)     = make_float4(m0, m1, m2, m3);
        *(float4*)(pb + (size_t)2 * NCH * CC) = make_float4(q0, q1, q2, q3);
    }
}

// ---------------- Kernel 2: reduce + prior-in-reg + rows ----------------
// 512 blocks x 256. Block = (b, 8 rows). In-block: reduce this b's partials ->
// h0 planes in LDS; prior rows from ne in registers; linearized-QK softmax;
// A write; msg via Wg*(A@h0); LN+head epilogue split across lane halves.
__global__ __launch_bounds__(256) void k_rows(P p) {
    __shared__ float pl[4 * CC];    // h0 planes [stat][col]
    __shared__ float stg[3 * CC];   // reduce staging
    int tid = threadIdx.x;
    int b = blockIdx.x >> 6, rb = blockIdx.x & 63;
    int wid = tid >> 6, lane = tid & 63;
    int row0 = rb * 8 + wid * 2;

    // ---- stage A: this b's partial reduction (each half-block: 32 chunks) ----
    int c4 = (tid & 127) * 4;
    int part = tid >> 7;
    const float* pS = p.pbuf + ((size_t)(b * 3 + 0) * NCH + part * 32) * CC + c4;
    const float* pM = p.pbuf + ((size_t)(b * 3 + 1) * NCH + part * 32) * CC + c4;
    const float* pQ = p.pbuf + ((size_t)(b * 3 + 2) * NCH + part * 32) * CC + c4;
    float as0 = 0.f, as1 = 0.f, as2 = 0.f, as3 = 0.f;
    float am0 = 0.f, am1 = 0.f, am2 = 0.f, am3 = 0.f;
    float aq0 = 0.f, aq1 = 0.f, aq2 = 0.f, aq3 = 0.f;
    #pragma unroll 8
    for (int i = 0; i < 32; i++) {
        float4 v = *(const float4*)(pS + (size_t)i * CC);
        as0 += v.x; as1 += v.y; as2 += v.z; as3 += v.w;
        float4 w = *(const float4*)(pM + (size_t)i * CC);
        am0 = fmaxf(am0, w.x); am1 = fmaxf(am1, w.y);
        am2 = fmaxf(am2, w.z); am3 = fmaxf(am3, w.w);
        float4 u = *(const float4*)(pQ + (size_t)i * CC);
        aq0 += u.x; aq1 += u.y; aq2 += u.z; aq3 += u.w;
    }
    if (part == 1) {
        *(float4*)&stg[0 * CC + c4] = make_float4(as0, as1, as2, as3);
        *(float4*)&stg[1 * CC + c4] = make_float4(am0, am1, am2, am3);
        *(float4*)&stg[2 * CC + c4] = make_float4(aq0, aq1, aq2, aq3);
    }

    // ---- stage B: prior rows (register-only, overlaps stage-A latency) ----
    float nr[2][16];
    #pragma unroll
    for (int rr = 0; rr < 2; rr++) {
        #pragma unroll
        for (int t = 0; t < 4; t++) {
            float4 v = *(const float4*)(p.ne + (size_t)(row0 + rr) * 16 + t * 4);
            nr[rr][4 * t] = v.x; nr[rr][4 * t + 1] = v.y;
            nr[rr][4 * t + 2] = v.z; nr[rr][4 * t + 3] = v.w;
        }
    }
    float pr0[8], pr1[8];
    #pragma unroll
    for (int j = 0; j < 8; j++) {
        int col = lane + 64 * j;
        float d0 = 0.f, d1 = 0.f;
        #pragma unroll
        for (int t = 0; t < 4; t++) {
            float4 v = *(const float4*)(p.ne + (size_t)col * 16 + t * 4);
            d0 = fmaf(nr[0][4 * t], v.x, d0); d0 = fmaf(nr[0][4 * t + 1], v.y, d0);
            d0 = fmaf(nr[0][4 * t + 2], v.z, d0); d0 = fmaf(nr[0][4 * t + 3], v.w, d0);
            d1 = fmaf(nr[1][4 * t], v.x, d1); d1 = fmaf(nr[1][4 * t + 1], v.y, d1);
            d1 = fmaf(nr[1][4 * t + 2], v.z, d1); d1 = fmaf(nr[1][4 * t + 3], v.w, d1);
        }
        pr0[j] = fmaxf(d0, 0.f);
        pr1[j] = fmaxf(d1, 0.f);
    }

    __syncthreads();
    if (part == 0) {
        float4 cs = *(const float4*)&stg[0 * CC + c4];
        float4 cm = *(const float4*)&stg[1 * CC + c4];
        float4 cq = *(const float4*)&stg[2 * CC + c4];
        float S[4] = {as0 + cs.x, as1 + cs.y, as2 + cs.z, as3 + cs.w};
        float M[4] = {fmaxf(am0, cm.x), fmaxf(am1, cm.y), fmaxf(am2, cm.z), fmaxf(am3, cm.w)};
        float Q[4] = {aq0 + cq.x, aq1 + cq.y, aq2 + cq.z, aq3 + cq.w};
        #pragma unroll
        for (int k = 0; k < 4; k++) {
            float m = S[k] * (1.f / LL);
            float sqm = Q[k] * (1.f / LL);
            float sd = sqrtf(fmaxf(sqm - m * m, 0.f));
            int col = c4 + k;
            pl[col] = m;
            pl[CC + col] = M[k];
            pl[2 * CC + col] = sd;
            pl[3 * CC + col] = sqm;
            if (rb == 0)
                *(float4*)(p.out + H0_OFF + ((size_t)b * CC + col) * 4) =
                    make_float4(m, M[k], sd, sqm);
        }
    }
    __syncthreads();

    // ---- stage C: linearized QK softmax + A + msg + head ----
    float sloc[2][4], u[2][4], c0[2];
    #pragma unroll
    for (int rr = 0; rr < 2; rr++) {
        int row = row0 + rr;
        float sv0 = pl[row], sv1 = pl[CC + row];
        float sv2 = pl[2 * CC + row], sv3 = pl[3 * CC + row];
        sloc[rr][0] = sv0; sloc[rr][1] = sv1; sloc[rr][2] = sv2; sloc[rr][3] = sv3;
        float uu0 = 0.f, uu1 = 0.f, uu2 = 0.f, uu3 = 0.f, cc = 0.f;
        #pragma unroll
        for (int i = 0; i < 16; i++) {
            float qi = p.bq[i];
            qi = fmaf(p.Wq[i * 4 + 0], sv0, qi);
            qi = fmaf(p.Wq[i * 4 + 1], sv1, qi);
            qi = fmaf(p.Wq[i * 4 + 2], sv2, qi);
            qi = fmaf(p.Wq[i * 4 + 3], sv3, qi);
            uu0 = fmaf(qi, p.Wk[i * 4 + 0], uu0);
            uu1 = fmaf(qi, p.Wk[i * 4 + 1], uu1);
            uu2 = fmaf(qi, p.Wk[i * 4 + 2], uu2);
            uu3 = fmaf(qi, p.Wk[i * 4 + 3], uu3);
            cc = fmaf(qi, p.bk[i], cc);
        }
        u[rr][0] = uu0; u[rr][1] = uu1; u[rr][2] = uu2; u[rr][3] = uu3;
        c0[rr] = cc;
    }

    float sv[2][8];
    float mx0 = -1e30f, mx1 = -1e30f;
    #pragma unroll
    for (int j = 0; j < 8; j++) {
        int col = lane + 64 * j;
        float h0c = pl[col], h1c = pl[CC + col];
        float h2c = pl[2 * CC + col], h3c = pl[3 * CC + col];
        float d0 = c0[0], d1 = c0[1];
        d0 = fmaf(u[0][0], h0c, d0); d1 = fmaf(u[1][0], h0c, d1);
        d0 = fmaf(u[0][1], h1c, d0); d1 = fmaf(u[1][1], h1c, d1);
        d0 = fmaf(u[0][2], h2c, d0); d1 = fmaf(u[1][2], h2c, d1);
        d0 = fmaf(u[0][3], h3c, d0); d1 = fmaf(u[1][3], h3c, d1);
        float v0 = fmaxf(d0, 0.f) + F_PRIOR_BETA * pr0[j] + (col == row0 ? 1.f : 0.f);
        float v1 = fmaxf(d1, 0.f) + F_PRIOR_BETA * pr1[j] + (col == row0 + 1 ? 1.f : 0.f);
        sv[0][j] = v0; sv[1][j] = v1;
        mx0 = fmaxf(mx0, v0); mx1 = fmaxf(mx1, v1);
    }
    #pragma unroll
    for (int o = 32; o; o >>= 1) {
        mx0 = fmaxf(mx0, __shfl_xor(mx0, o));
        mx1 = fmaxf(mx1, __shfl_xor(mx1, o));
    }

    float ls0 = 0.f, ls1 = 0.f;
    float T0[4] = {0.f, 0.f, 0.f, 0.f}, T1[4] = {0.f, 0.f, 0.f, 0.f};
    #pragma unroll
    for (int j = 0; j < 8; j++) {
        int col = lane + 64 * j;
        float e0 = expf(sv[0][j] - mx0);
        float e1 = expf(sv[1][j] - mx1);
        sv[0][j] = e0; sv[1][j] = e1;
        ls0 += e0; ls1 += e1;
        float h0c = pl[col], h1c = pl[CC + col];
        float h2c = pl[2 * CC + col], h3c = pl[3 * CC + col];
        T0[0] = fmaf(e0, h0c, T0[0]); T1[0] = fmaf(e1, h0c, T1[0]);
        T0[1] = fmaf(e0, h1c, T0[1]); T1[1] = fmaf(e1, h1c, T1[1]);
        T0[2] = fmaf(e0, h2c, T0[2]); T1[2] = fmaf(e1, h2c, T1[2]);
        T0[3] = fmaf(e0, h3c, T0[3]); T1[3] = fmaf(e1, h3c, T1[3]);
    }
    #pragma unroll
    for (int o = 32; o; o >>= 1) {
        ls0 += __shfl_xor(ls0, o); ls1 += __shfl_xor(ls1, o);
        T0[0] += __shfl_xor(T0[0], o); T1[0] += __shfl_xor(T1[0], o);
        T0[1] += __shfl_xor(T0[1], o); T1[1] += __shfl_xor(T1[1], o);
        T0[2] += __shfl_xor(T0[2], o); T1[2] += __shfl_xor(T1[2], o);
        T0[3] += __shfl_xor(T0[3], o); T1[3] += __shfl_xor(T1[3], o);
    }
    float inv0 = 1.f / ls0, inv1 = 1.f / ls1;

    float* arow = p.out + A_OFF + ((size_t)b * CC + row0) * CC;
    #pragma unroll
    for (int j = 0; j < 8; j++) {
        arow[lane + 64 * j]      = sv[0][j] * inv0;
        arow[CC + lane + 64 * j] = sv[1][j] * inv1;
    }

    // ---- epilogue: lanes 0-31 handle row0, lanes 32-63 handle row0+1 ----
    int rr = lane >> 5;
    float inv = rr ? inv1 : inv0;
    float Ta = (rr ? T1[0] : T0[0]) * inv;
    float Tb = (rr ? T1[1] : T0[1]) * inv;
    float Tc = (rr ? T1[2] : T0[2]) * inv;
    float Td = (rr ? T1[3] : T0[3]) * inv;
    float s20 = rr ? sloc[1][0] : sloc[0][0];
    float s21 = rr ? sloc[1][1] : sloc[0][1];
    float s22 = rr ? sloc[1][2] : sloc[0][2];
    float s23 = rr ? sloc[1][3] : sloc[0][3];

    float gcomb[16];
    #pragma unroll
    for (int h = 0; h < 16; h++) {
        float w0 = p.Wg[h * 4 + 0], w1 = p.Wg[h * 4 + 1];
        float w2 = p.Wg[h * 4 + 2], w3 = p.Wg[h * 4 + 3];
        float bgh = p.bg[h];
        float hg = bgh;
        hg = fmaf(w0, s20, hg); hg = fmaf(w1, s21, hg);
        hg = fmaf(w2, s22, hg); hg = fmaf(w3, s23, hg);
        float mg = bgh;
        mg = fmaf(w0, Ta, mg); mg = fmaf(w1, Tb, mg);
        mg = fmaf(w2, Tc, mg); mg = fmaf(w3, Td, mg);
        gcomb[h] = hg + F_GRAPH_LAMBDA * fmaxf(mg, 0.f);
    }
    float t1v[16];
    #pragma unroll
    for (int i = 0; i < 16; i++) {
        float a = p.bl1[i];
        a = fmaf(p.Wl1[i * 4 + 0], s20, a);
        a = fmaf(p.Wl1[i * 4 + 1], s21, a);
        a = fmaf(p.Wl1[i * 4 + 2], s22, a);
        a = fmaf(p.Wl1[i * 4 + 3], s23, a);
        t1v[i] = fmaxf(a, 0.f);
    }
    float hvec[16];
    float mu = 0.f;
    #pragma unroll
    for (int h = 0; h < 16; h++) {
        float hl = p.bl2[h];
        #pragma unroll
        for (int j = 0; j < 16; j++) hl = fmaf(p.Wl2[h * 16 + j], t1v[j], hl);
        float hv = hl + F_FUSION_BETA * gcomb[h];
        hvec[h] = hv;
        mu += hv;
    }
    mu *= (1.f / 16.f);
    float var = 0.f;
    #pragma unroll
    for (int h = 0; h < 16; h++) { float d = hvec[h] - mu; var = fmaf(d, d, var); }
    var *= (1.f / 16.f);
    float istd = 1.f / sqrtf(var + F_LN_EPS);
    float hn[16];
    #pragma unroll
    for (int h = 0; h < 16; h++) hn[h] = (hvec[h] - mu) * istd * p.lng[h] + p.lnb[h];

    float acc2 = p.bo[0];
    #pragma unroll
    for (int o = 0; o < 16; o++) {
        float f = p.bf[o];
        #pragma unroll
        for (int t = 0; t < 16; t++) f = fmaf(p.Wf[o * 16 + t], hn[t], f);
        acc2 = fmaf(p.Wo[o], fmaxf(f, 0.f), acc2);
    }
    float alpha = F_ALPHA_BASE + F_ALPHA_SCALE * tanhf(acc2);
    if ((lane & 31) == 0) p.out[(size_t)b * CC + row0 + rr] = alpha;
}

extern "C" void kernel_launch(void* const* d_in, const int* in_sizes, int n_in,
                              void* d_out, int out_size, void* d_ws, size_t ws_size,
                              hipStream_t stream) {
    P p;
    p.res = (const float*)d_in[0];
    p.ne  = (const float*)d_in[1];
    p.Wl1 = (const float*)d_in[2];
    p.bl1 = (const float*)d_in[3];
    p.Wl2 = (const float*)d_in[4];
    p.bl2 = (const float*)d_in[5];
    p.Wg  = (const float*)d_in[6];
    p.bg  = (const float*)d_in[7];
    p.Wq  = (const float*)d_in[8];
    p.bq  = (const float*)d_in[9];
    p.Wk  = (const float*)d_in[10];
    p.bk  = (const float*)d_in[11];
    p.Wf  = (const float*)d_in[12];
    p.bf  = (const float*)d_in[13];
    p.Wo  = (const float*)d_in[14];
    p.bo  = (const float*)d_in[15];
    p.lng = (const float*)d_in[16];
    p.lnb = (const float*)d_in[17];
    p.out  = (float*)d_out;
    p.pbuf = (float*)d_ws;   // [B][3][NCH][C] = 3.1 MB

    k_stats<<<BB * NCH, 256, 0, stream>>>(p);
    k_rows<<<BB * 64, 256, 0, stream>>>(p);
}

// Round 7
// 50.047 us; speedup vs baseline: 3.9288x; 1.1135x over previous
//
#include <hip/hip_runtime.h>
#include <math.h>

#define BB 8
#define LL 8192
#define CC 512
#define NCH 64    // stat chunks per b (128 rows each)

#define H0_OFF (BB*CC)            // 4096
#define A_OFF  (H0_OFF + BB*CC*4) // 20480

#define F_ALPHA_BASE 1.2f
#define F_ALPHA_SCALE 0.3f
#define F_GRAPH_LAMBDA 0.3f
#define F_FUSION_BETA 0.1f
#define F_PRIOR_BETA 0.2f
#define F_LN_EPS 1e-5f

struct P {
    const float* res; const float* ne;
    const float* Wl1; const float* bl1; const float* Wl2; const float* bl2;
    const float* Wg;  const float* bg;  const float* Wq;  const float* bq;
    const float* Wk;  const float* bk;  const float* Wf;  const float* bf;
    const float* Wo;  const float* bo;  const float* lng; const float* lnb;
    float* out; float* pbuf; float* h0ws;
};

// ---------------- Kernel 1: stats partials (UNCHANGED from R6) ----------------
__global__ __launch_bounds__(256) void k_stats(P p) {
    __shared__ float smem[3 * CC];
    int b = blockIdx.x >> 6, cb = blockIdx.x & 63;
    int sub = threadIdx.x >> 7;
    int c4 = (threadIdx.x & 127) * 4;
    const float* base = p.res + ((size_t)b * LL + cb * 128 + sub * 64) * CC + c4;
    float s0 = 0.f, s1 = 0.f, s2 = 0.f, s3 = 0.f;
    float m0 = 0.f, m1 = 0.f, m2 = 0.f, m3 = 0.f;
    float q0 = 0.f, q1 = 0.f, q2 = 0.f, q3 = 0.f;
    #pragma unroll 8
    for (int r = 0; r < 64; r++) {
        float4 v = *(const float4*)(base + (size_t)r * CC);
        s0 += fabsf(v.x); s1 += fabsf(v.y); s2 += fabsf(v.z); s3 += fabsf(v.w);
        m0 = fmaxf(m0, fabsf(v.x)); m1 = fmaxf(m1, fabsf(v.y));
        m2 = fmaxf(m2, fabsf(v.z)); m3 = fmaxf(m3, fabsf(v.w));
        q0 = fmaf(v.x, v.x, q0); q1 = fmaf(v.y, v.y, q1);
        q2 = fmaf(v.z, v.z, q2); q3 = fmaf(v.w, v.w, q3);
    }
    if (sub == 1) {
        *(float4*)&smem[0 * CC + c4] = make_float4(s0, s1, s2, s3);
        *(float4*)&smem[1 * CC + c4] = make_float4(m0, m1, m2, m3);
        *(float4*)&smem[2 * CC + c4] = make_float4(q0, q1, q2, q3);
    }
    __syncthreads();
    if (sub == 0) {
        float4 cs = *(const float4*)&smem[0 * CC + c4];
        float4 cm = *(const float4*)&smem[1 * CC + c4];
        float4 cq = *(const float4*)&smem[2 * CC + c4];
        s0 += cs.x; s1 += cs.y; s2 += cs.z; s3 += cs.w;
        m0 = fmaxf(m0, cm.x); m1 = fmaxf(m1, cm.y);
        m2 = fmaxf(m2, cm.z); m3 = fmaxf(m3, cm.w);
        q0 += cq.x; q1 += cq.y; q2 += cq.z; q3 += cq.w;
        float* pb = p.pbuf + ((size_t)(b * 3) * NCH + cb) * CC + c4;
        *(float4*)(pb)                        = make_float4(s0, s1, s2, s3);
        *(float4*)(pb + (size_t)NCH * CC)     = make_float4(m0, m1, m2, m3);
        *(float4*)(pb + (size_t)2 * NCH * CC) = make_float4(q0, q1, q2, q3);
    }
}

// ---------------- Kernel 2: tiny h0 finish ----------------
// 64 blocks x 256. Block = 64 (b,c) pairs; wave w reduces chunk-quarter w
// (coalesced 256B rows), LDS combine across waves; wave 0 writes h0.
__global__ __launch_bounds__(256) void k_red(P p) {
    __shared__ float red[4][3][64];
    int w = threadIdx.x >> 6, lane = threadIdx.x & 63;
    int b = blockIdx.x >> 3;
    int c = (blockIdx.x & 7) * 64 + lane;
    const float* pS = p.pbuf + ((size_t)(b * 3 + 0) * NCH + w * 16) * CC + c;
    const float* pM = p.pbuf + ((size_t)(b * 3 + 1) * NCH + w * 16) * CC + c;
    const float* pQ = p.pbuf + ((size_t)(b * 3 + 2) * NCH + w * 16) * CC + c;
    float sum = 0.f, mx = 0.f, sq = 0.f;
    #pragma unroll
    for (int i = 0; i < 16; i++) {
        sum += pS[(size_t)i * CC];
        mx = fmaxf(mx, pM[(size_t)i * CC]);
        sq += pQ[(size_t)i * CC];
    }
    red[w][0][lane] = sum;
    red[w][1][lane] = mx;
    red[w][2][lane] = sq;
    __syncthreads();
    if (w == 0) {
        float ts = red[0][0][lane] + red[1][0][lane] + red[2][0][lane] + red[3][0][lane];
        float tm = fmaxf(fmaxf(red[0][1][lane], red[1][1][lane]),
                         fmaxf(red[2][1][lane], red[3][1][lane]));
        float tq = red[0][2][lane] + red[1][2][lane] + red[2][2][lane] + red[3][2][lane];
        float m = ts * (1.f / LL);
        float sqm = tq * (1.f / LL);
        float sd = sqrtf(fmaxf(sqm - m * m, 0.f));
        float4 h0v = make_float4(m, tm, sd, sqm);
        size_t g = (size_t)b * CC + c;
        *(float4*)(p.h0ws + g * 4) = h0v;
        *(float4*)(p.out + H0_OFF + g * 4) = h0v;
    }
}

// ---------------- Kernel 3: rows (light) ----------------
// 512 blocks x 256. Block = (b, 8 rows). Reads 8KB h0 + ne; writes A + alpha.
__global__ __launch_bounds__(256) void k_rows(P p) {
    __shared__ float pl[4 * CC];    // h0 planes [stat][col]
    int tid = threadIdx.x;
    int b = blockIdx.x >> 6, rb = blockIdx.x & 63;
    int wid = tid >> 6, lane = tid & 63;
    int row0 = rb * 8 + wid * 2;

    #pragma unroll
    for (int ccy = 0; ccy < 2; ccy++) {
        int col = tid + ccy * 256;
        float4 hv = *(const float4*)(p.h0ws + ((size_t)b * CC + col) * 4);
        pl[col] = hv.x;
        pl[CC + col] = hv.y;
        pl[2 * CC + col] = hv.z;
        pl[3 * CC + col] = hv.w;
    }

    // prior rows from ne in registers (overlaps the staging latency)
    float nr[2][16];
    #pragma unroll
    for (int rr = 0; rr < 2; rr++) {
        #pragma unroll
        for (int t = 0; t < 4; t++) {
            float4 v = *(const float4*)(p.ne + (size_t)(row0 + rr) * 16 + t * 4);
            nr[rr][4 * t] = v.x; nr[rr][4 * t + 1] = v.y;
            nr[rr][4 * t + 2] = v.z; nr[rr][4 * t + 3] = v.w;
        }
    }
    float pr0[8], pr1[8];
    #pragma unroll
    for (int j = 0; j < 8; j++) {
        int col = lane + 64 * j;
        float d0 = 0.f, d1 = 0.f;
        #pragma unroll
        for (int t = 0; t < 4; t++) {
            float4 v = *(const float4*)(p.ne + (size_t)col * 16 + t * 4);
            d0 = fmaf(nr[0][4 * t], v.x, d0); d0 = fmaf(nr[0][4 * t + 1], v.y, d0);
            d0 = fmaf(nr[0][4 * t + 2], v.z, d0); d0 = fmaf(nr[0][4 * t + 3], v.w, d0);
            d1 = fmaf(nr[1][4 * t], v.x, d1); d1 = fmaf(nr[1][4 * t + 1], v.y, d1);
            d1 = fmaf(nr[1][4 * t + 2], v.z, d1); d1 = fmaf(nr[1][4 * t + 3], v.w, d1);
        }
        pr0[j] = fmaxf(d0, 0.f);
        pr1[j] = fmaxf(d1, 0.f);
    }
    __syncthreads();

    // linearized QK: per row, u = Wk^T (Wq s + bq), c0 = q·bk
    float sloc[2][4], u[2][4], c0[2];
    #pragma unroll
    for (int rr = 0; rr < 2; rr++) {
        int row = row0 + rr;
        float sv0 = pl[row], sv1 = pl[CC + row];
        float sv2 = pl[2 * CC + row], sv3 = pl[3 * CC + row];
        sloc[rr][0] = sv0; sloc[rr][1] = sv1; sloc[rr][2] = sv2; sloc[rr][3] = sv3;
        float uu0 = 0.f, uu1 = 0.f, uu2 = 0.f, uu3 = 0.f, cc = 0.f;
        #pragma unroll
        for (int i = 0; i < 16; i++) {
            float qi = p.bq[i];
            qi = fmaf(p.Wq[i * 4 + 0], sv0, qi);
            qi = fmaf(p.Wq[i * 4 + 1], sv1, qi);
            qi = fmaf(p.Wq[i * 4 + 2], sv2, qi);
            qi = fmaf(p.Wq[i * 4 + 3], sv3, qi);
            uu0 = fmaf(qi, p.Wk[i * 4 + 0], uu0);
            uu1 = fmaf(qi, p.Wk[i * 4 + 1], uu1);
            uu2 = fmaf(qi, p.Wk[i * 4 + 2], uu2);
            uu3 = fmaf(qi, p.Wk[i * 4 + 3], uu3);
            cc = fmaf(qi, p.bk[i], cc);
        }
        u[rr][0] = uu0; u[rr][1] = uu1; u[rr][2] = uu2; u[rr][3] = uu3;
        c0[rr] = cc;
    }

    float sv[2][8];
    float mx0 = -1e30f, mx1 = -1e30f;
    #pragma unroll
    for (int j = 0; j < 8; j++) {
        int col = lane + 64 * j;
        float h0c = pl[col], h1c = pl[CC + col];
        float h2c = pl[2 * CC + col], h3c = pl[3 * CC + col];
        float d0 = c0[0], d1 = c0[1];
        d0 = fmaf(u[0][0], h0c, d0); d1 = fmaf(u[1][0], h0c, d1);
        d0 = fmaf(u[0][1], h1c, d0); d1 = fmaf(u[1][1], h1c, d1);
        d0 = fmaf(u[0][2], h2c, d0); d1 = fmaf(u[1][2], h2c, d1);
        d0 = fmaf(u[0][3], h3c, d0); d1 = fmaf(u[1][3], h3c, d1);
        float v0 = fmaxf(d0, 0.f) + F_PRIOR_BETA * pr0[j] + (col == row0 ? 1.f : 0.f);
        float v1 = fmaxf(d1, 0.f) + F_PRIOR_BETA * pr1[j] + (col == row0 + 1 ? 1.f : 0.f);
        sv[0][j] = v0; sv[1][j] = v1;
        mx0 = fmaxf(mx0, v0); mx1 = fmaxf(mx1, v1);
    }
    #pragma unroll
    for (int o = 32; o; o >>= 1) {
        mx0 = fmaxf(mx0, __shfl_xor(mx0, o));
        mx1 = fmaxf(mx1, __shfl_xor(mx1, o));
    }

    float ls0 = 0.f, ls1 = 0.f;
    float T0[4] = {0.f, 0.f, 0.f, 0.f}, T1[4] = {0.f, 0.f, 0.f, 0.f};
    #pragma unroll
    for (int j = 0; j < 8; j++) {
        int col = lane + 64 * j;
        float e0 = expf(sv[0][j] - mx0);
        float e1 = expf(sv[1][j] - mx1);
        sv[0][j] = e0; sv[1][j] = e1;
        ls0 += e0; ls1 += e1;
        float h0c = pl[col], h1c = pl[CC + col];
        float h2c = pl[2 * CC + col], h3c = pl[3 * CC + col];
        T0[0] = fmaf(e0, h0c, T0[0]); T1[0] = fmaf(e1, h0c, T1[0]);
        T0[1] = fmaf(e0, h1c, T0[1]); T1[1] = fmaf(e1, h1c, T1[1]);
        T0[2] = fmaf(e0, h2c, T0[2]); T1[2] = fmaf(e1, h2c, T1[2]);
        T0[3] = fmaf(e0, h3c, T0[3]); T1[3] = fmaf(e1, h3c, T1[3]);
    }
    #pragma unroll
    for (int o = 32; o; o >>= 1) {
        ls0 += __shfl_xor(ls0, o); ls1 += __shfl_xor(ls1, o);
        T0[0] += __shfl_xor(T0[0], o); T1[0] += __shfl_xor(T1[0], o);
        T0[1] += __shfl_xor(T0[1], o); T1[1] += __shfl_xor(T1[1], o);
        T0[2] += __shfl_xor(T0[2], o); T1[2] += __shfl_xor(T1[2], o);
        T0[3] += __shfl_xor(T0[3], o); T1[3] += __shfl_xor(T1[3], o);
    }
    float inv0 = 1.f / ls0, inv1 = 1.f / ls1;

    float* arow = p.out + A_OFF + ((size_t)b * CC + row0) * CC;
    #pragma unroll
    for (int j = 0; j < 8; j++) {
        arow[lane + 64 * j]      = sv[0][j] * inv0;
        arow[CC + lane + 64 * j] = sv[1][j] * inv1;
    }

    // epilogue: lanes 0-31 handle row0, lanes 32-63 handle row0+1
    int rr = lane >> 5;
    float inv = rr ? inv1 : inv0;
    float Ta = (rr ? T1[0] : T0[0]) * inv;
    float Tb = (rr ? T1[1] : T0[1]) * inv;
    float Tc = (rr ? T1[2] : T0[2]) * inv;
    float Td = (rr ? T1[3] : T0[3]) * inv;
    float s20 = rr ? sloc[1][0] : sloc[0][0];
    float s21 = rr ? sloc[1][1] : sloc[0][1];
    float s22 = rr ? sloc[1][2] : sloc[0][2];
    float s23 = rr ? sloc[1][3] : sloc[0][3];

    float gcomb[16];
    #pragma unroll
    for (int h = 0; h < 16; h++) {
        float w0 = p.Wg[h * 4 + 0], w1 = p.Wg[h * 4 + 1];
        float w2 = p.Wg[h * 4 + 2], w3 = p.Wg[h * 4 + 3];
        float bgh = p.bg[h];
        float hg = bgh;
        hg = fmaf(w0, s20, hg); hg = fmaf(w1, s21, hg);
        hg = fmaf(w2, s22, hg); hg = fmaf(w3, s23, hg);
        float mg = bgh;
        mg = fmaf(w0, Ta, mg); mg = fmaf(w1, Tb, mg);
        mg = fmaf(w2, Tc, mg); mg = fmaf(w3, Td, mg);
        gcomb[h] = hg + F_GRAPH_LAMBDA * fmaxf(mg, 0.f);
    }
    float t1v[16];
    #pragma unroll
    for (int i = 0; i < 16; i++) {
        float a = p.bl1[i];
        a = fmaf(p.Wl1[i * 4 + 0], s20, a);
        a = fmaf(p.Wl1[i * 4 + 1], s21, a);
        a = fmaf(p.Wl1[i * 4 + 2], s22, a);
        a = fmaf(p.Wl1[i * 4 + 3], s23, a);
        t1v[i] = fmaxf(a, 0.f);
    }
    float hvec[16];
    float mu = 0.f;
    #pragma unroll
    for (int h = 0; h < 16; h++) {
        float hl = p.bl2[h];
        #pragma unroll
        for (int j = 0; j < 16; j++) hl = fmaf(p.Wl2[h * 16 + j], t1v[j], hl);
        float hv = hl + F_FUSION_BETA * gcomb[h];
        hvec[h] = hv;
        mu += hv;
    }
    mu *= (1.f / 16.f);
    float var = 0.f;
    #pragma unroll
    for (int h = 0; h < 16; h++) { float d = hvec[h] - mu; var = fmaf(d, d, var); }
    var *= (1.f / 16.f);
    float istd = 1.f / sqrtf(var + F_LN_EPS);
    float hn[16];
    #pragma unroll
    for (int h = 0; h < 16; h++) hn[h] = (hvec[h] - mu) * istd * p.lng[h] + p.lnb[h];

    float acc2 = p.bo[0];
    #pragma unroll
    for (int o = 0; o < 16; o++) {
        float f = p.bf[o];
        #pragma unroll
        for (int t = 0; t < 16; t++) f = fmaf(p.Wf[o * 16 + t], hn[t], f);
        acc2 = fmaf(p.Wo[o], fmaxf(f, 0.f), acc2);
    }
    float alpha = F_ALPHA_BASE + F_ALPHA_SCALE * tanhf(acc2);
    if ((lane & 31) == 0) p.out[(size_t)b * CC + row0 + rr] = alpha;
}

extern "C" void kernel_launch(void* const* d_in, const int* in_sizes, int n_in,
                              void* d_out, int out_size, void* d_ws, size_t ws_size,
                              hipStream_t stream) {
    P p;
    p.res = (const float*)d_in[0];
    p.ne  = (const float*)d_in[1];
    p.Wl1 = (const float*)d_in[2];
    p.bl1 = (const float*)d_in[3];
    p.Wl2 = (const float*)d_in[4];
    p.bl2 = (const float*)d_in[5];
    p.Wg  = (const float*)d_in[6];
    p.bg  = (const float*)d_in[7];
    p.Wq  = (const float*)d_in[8];
    p.bq  = (const float*)d_in[9];
    p.Wk  = (const float*)d_in[10];
    p.bk  = (const float*)d_in[11];
    p.Wf  = (const float*)d_in[12];
    p.bf  = (const float*)d_in[13];
    p.Wo  = (const float*)d_in[14];
    p.bo  = (const float*)d_in[15];
    p.lng = (const float*)d_in[16];
    p.lnb = (const float*)d_in[17];
    p.out  = (float*)d_out;
    p.pbuf = (float*)d_ws;                                  // [B][3][NCH][C] = 3.1 MB
    p.h0ws = (float*)d_ws + (size_t)BB * 3 * NCH * CC;      // [B][C][4] = 64 KB

    k_stats<<<BB * NCH, 256, 0, stream>>>(p);
    k_red<<<64, 256, 0, stream>>>(p);
    k_rows<<<BB * 64, 256, 0, stream>>>(p);
}